// Round 1
// 826.434 us; speedup vs baseline: 1.0368x; 1.0368x over previous
//
#include <hip/hip_runtime.h>
#include <cmath>

// ============================================================================
// ConvMod1D fused kernel — round 3: occupancy via 6-slot schedule.
// TL=32 positions/block (halo 12 each side -> EXT=56). 6 LDS slots of
// [pos][chan] bf16, row stride RS=72 u16 -> ~50.3 KB LDS => 3 blocks/CU,
// 24 waves/CU (was 9 slots / 75.5 KB / 2 blocks / 16 waves).
// Enablers:
//  * in-place pointwise MFMA: __syncthreads() between k-loop (all reads) and
//    the store loop makes out==in race-free (pv2, mul2, pv3, p3a).
//  * in-place depthwise: read window into regs -> barrier -> write (win16,
//    <=1 task/wave: a2 tasks=6, a3 tasks=6).
//  * t = a*pv elementwise fused into the depthwise store (mul_ph removed).
//  * LN1 stats precomputed by ln1pre_kernel (coalesced) into d_ws; removes
//    the 112-thread x 128-strided-scalar-load ln1_stats phase.
//
// Slot schedule (S0..S5, liveness checked; stale data only ever feeds
// masked MFMA columns / is finite bf16):
//  pre: meanA/rstdA <- stats | P0 xs0n->S0, xs1n->S1
//  P1 g1->S2 [0,56), pv1->S3 [3,53), pwv12->S4 [2,54)
//  P2 a1=dw7(S2)->S5 + t1=a1*pv1 in-place S3   [3,53)
//  P3 mul1=pw(S3)->S2, x1low=dw3(S4)+S5->S1    [3,53)
//  P4 ln2 over {S1,S2} [3,53)
//  P5 xs2n->S0 [6,50), g2->{S3,S4} [3,53), pv2 INPL {S1,S2} [7,49)
//  P6 pwv22: S0->S5 [6,50), a2=dw9 INPL {S3,S4} + t2 in-place {S1,S2} [7,49)
//  P7 p2a: {S3,S4}->S0 [7,49), mul2 INPL {S1,S2} [7,49)
//  P8 x2low=dw3(S5)+S0->S3 [7,49)
//  P9 ln3 over {S3,S1,S2} [7,49)
//  P10 g3->{S4,S5,S0} [7,49), pv3 INPL {S3,S1,S2} [12,44)
//  P11 a3=dw11 INPL {S4,S5,S0} + t3 in-place {S3,S1,S2} [12,44)
//  P12 mul3: pw(t3)->OUT[64:256], p3a INPL {S4,S5,S0}->S4, xs3n->S5 [11,45)
//  P13 pwv32: S5->S0 [11,45)
//  P14 x3=dw3(S0)+S4->OUT[0:64]
// ============================================================================

using u16 = unsigned short;
typedef short shrt8 __attribute__((ext_vector_type(8)));
typedef short shrt4 __attribute__((ext_vector_type(4)));
typedef float f32x4 __attribute__((ext_vector_type(4)));

#define DEVI __device__ __forceinline__

static constexpr int EXT  = 56;          // 32 useful + 2*12 halo
static constexpr int RS   = 72;          // row stride in u16 (64 + 8 pad)
static constexpr int SLOT = EXT * RS;    // 4032 u16 = 8064 B
static constexpr int NW   = 8;

DEVI u16 f2bf(float f) {                 // RNE fp32 -> bf16
    unsigned u = __float_as_uint(f);
    u += 0x7FFFu + ((u >> 16) & 1u);
    return (u16)(u >> 16);
}
DEVI float bf2f(u16 h) { return __uint_as_float(((unsigned)h) << 16); }

// exact-GELU via Abramowitz-Stegun 7.1.26 erf (|err| <= 1.5e-7, branch-free)
DEVI float gelu_f(float x) {
    const float y  = x * 0.70710678118654752f;
    const float ay = fabsf(y);
    const float t  = __builtin_amdgcn_rcpf(fmaf(0.3275911f, ay, 1.0f));
    float p = 1.061405429f;
    p = fmaf(p, t, -1.453152027f);
    p = fmaf(p, t,  1.421413741f);
    p = fmaf(p, t, -0.284496736f);
    p = fmaf(p, t,  0.254829592f);
    float er = 1.0f - p * t * __expf(-ay * ay);
    er = copysignf(er, y);
    return 0.5f * x * (1.0f + er);
}

struct SL { int a, b, c; };
DEVI int slotOf(SL s, int ch) { return ch < 64 ? s.a : (ch < 128 ? s.b : s.c); }

// ---------------- pointwise conv via MFMA ------------------------------------
// INPL: out slots alias in slots -> barrier between k-loop (reads) and store.
template<int O, int C, bool GELU, bool TOG, bool INPL>
DEVI void pw_mfma(u16* sh, SL in, SL out, const u16* Wb, const float* bias,
                  int elo, int ehi, int l0,
                  float* outg = nullptr, int bidx = 0, int ochan = 0) {
    constexpr int MR = O / 64;           // m-tiles per wave (4 m-splits)
    constexpr int KT = C / 32;
    const int lane = threadIdx.x & 63;
    const int wv   = threadIdx.x >> 6;
    const int mw = wv >> 1, nw = wv & 1;
    const int col  = lane & 15;
    const int quad = lane >> 4;
    const int mrow = mw * (MR * 16) + col;
    const int kq   = quad * 8;
    const int crow = mw * (MR * 16) + quad * 4;

    f32x4 acc[MR][2];
    #pragma unroll
    for (int mi = 0; mi < MR; ++mi) {
        const f32x4 bv = *(const f32x4*)(bias + crow + mi * 16);
        acc[mi][0] = bv; acc[mi][1] = bv;
    }
    bool act[2]; int bpos[2];
    #pragma unroll
    for (int ni = 0; ni < 2; ++ni) {
        const int nt = nw * 2 + ni;
        act[ni] = (nt * 16 < ehi) && (nt * 16 + 16 > elo);
        int p = nt * 16 + col; if (p > EXT - 1) p = EXT - 1;  // masked cols only
        bpos[ni] = p;
    }
    #pragma unroll
    for (int kt = 0; kt < KT; ++kt) {
        shrt8 af[MR];
        #pragma unroll
        for (int mi = 0; mi < MR; ++mi)
            af[mi] = *(const shrt8*)(Wb + (size_t)(mrow + mi * 16) * C + kt * 32 + kq);
        const int k0 = kt * 32;
        const u16* bs = sh + slotOf(in, k0) * SLOT + ((k0 & 63) + kq);
        #pragma unroll
        for (int ni = 0; ni < 2; ++ni) {
            if (!act[ni]) continue;
            const shrt8 bf = *(const shrt8*)(bs + bpos[ni] * RS);
            #pragma unroll
            for (int mi = 0; mi < MR; ++mi)
                acc[mi][ni] = __builtin_amdgcn_mfma_f32_16x16x32_bf16(af[mi], bf, acc[mi][ni], 0, 0, 0);
        }
    }
    if (INPL) __syncthreads();           // all reads done before any store
    #pragma unroll
    for (int ni = 0; ni < 2; ++ni) {
        if (!act[ni]) continue;
        const int e = (nw * 2 + ni) * 16 + col;
        if (e < elo || e >= ehi) continue;
        const int l = l0 + e;
        #pragma unroll
        for (int mi = 0; mi < MR; ++mi) {
            f32x4 v = acc[mi][ni];
            if (GELU) { v[0]=gelu_f(v[0]); v[1]=gelu_f(v[1]); v[2]=gelu_f(v[2]); v[3]=gelu_f(v[3]); }
            const int ch = crow + mi * 16;
            if (TOG) {
                float* og = outg + ((size_t)bidx * 256 + ochan + ch) * 4096 + l;
                og[0] = v[0]; og[4096] = v[1]; og[2*4096] = v[2]; og[3*4096] = v[3];
            } else {
                const bool gv = (unsigned)l < 4096u;
                shrt4 pk;
                pk[0] = gv ? (short)f2bf(v[0]) : (short)0;
                pk[1] = gv ? (short)f2bf(v[1]) : (short)0;
                pk[2] = gv ? (short)f2bf(v[2]) : (short)0;
                pk[3] = gv ? (short)f2bf(v[3]) : (short)0;
                *(shrt4*)(sh + slotOf(out, ch) * SLOT + e * RS + (ch & 63)) = pk;
            }
        }
    }
}

// ---------------- depthwise conv fused with t = a*v, optional in-place -------
// One window of WIN positions per wave (tasks = (C/64)*nwin must be <= NW).
// INPL: a-output aliases the input slots -> read window into regs, barrier,
// then write. The v-multiply is element-wise in-place (thread-private RMW).
template<int C, int K, int PAD, int WIN, bool INPL>
DEVI void dw_mul(u16* sh, SL g, SL ao, SL v, const float* W, const float* bias,
                 int elo, int ehi) {
    const int lane = threadIdx.x & 63;
    const int wv   = threadIdx.x >> 6;
    const int nwin  = (ehi - elo + WIN - 1) / WIN;
    const int tasks = (C / 64) * nwin;       // <= NW by construction
    const bool have = wv < tasks;
    float r[K + WIN - 1];
    float wk[K];
    float bo = 0.f;
    int c = 0, e0 = 0;
    if (have) {
        const int cb = wv / nwin, wi = wv - cb * nwin;
        c = cb * 64 + lane;
        #pragma unroll
        for (int k = 0; k < K; ++k) wk[k] = W[c * K + k];
        bo = bias[c];
        e0 = elo + wi * WIN;
        const u16* si = sh + slotOf(g, c) * SLOT + lane;
        #pragma unroll
        for (int m = 0; m < K + WIN - 1; ++m) {
            int e = e0 - PAD + m; if (e > EXT - 1) e = EXT - 1;  // feeds masked outputs only
            r[m] = bf2f(si[e * RS]);
        }
    }
    if (INPL) __syncthreads();               // all reads done before any write
    if (have) {
        u16* sa = sh + slotOf(ao, c) * SLOT + lane;
        u16* sv = sh + slotOf(v, c) * SLOT + lane;
        #pragma unroll
        for (int j = 0; j < WIN; ++j) {
            const int e = e0 + j;
            if (e >= ehi) break;
            float acc = bo;
            #pragma unroll
            for (int k = 0; k < K; ++k) acc = fmaf(wk[k], r[j + k], acc);
            sa[e * RS] = f2bf(acc);                               // a
            sv[e * RS] = f2bf(acc * bf2f(sv[e * RS]));            // t = a*v (v masked 0 OOB)
        }
    }
}

// ---------------- depthwise conv (VALU), chan-per-lane, 8-pos windows --------
template<int C, int K, int PAD, bool ADD>
DEVI void dw_ph(u16* sh, SL in, SL add, SL out, const float* W, const float* bias,
                int elo, int ehi, int l0) {
    const int lane = threadIdx.x & 63;
    const int wv   = threadIdx.x >> 6;
    const int nwin = (ehi - elo + 7) >> 3;
    const int tasks = (C / 64) * nwin;
    for (int t = wv; t < tasks; t += NW) {
        const int cb = t / nwin, wi = t - cb * nwin;
        const int c = cb * 64 + lane;
        float wk[K];
        #pragma unroll
        for (int k = 0; k < K; ++k) wk[k] = W[c * K + k];
        const float bo = bias[c];
        const int e0 = elo + wi * 8;
        const u16* si = sh + slotOf(in, c) * SLOT + lane;
        const u16* sa = ADD ? (sh + slotOf(add, c) * SLOT + lane) : nullptr;
        u16* so = sh + slotOf(out, c) * SLOT + lane;
        float r[K + 7];
        #pragma unroll
        for (int m = 0; m < K + 7; ++m) {
            int e = e0 - PAD + m; if (e > EXT - 1) e = EXT - 1;  // feeds masked outputs only
            r[m] = bf2f(si[e * RS]);
        }
        #pragma unroll
        for (int j = 0; j < 8; ++j) {
            const int e = e0 + j;
            if (e >= ehi) break;
            float acc = bo;
            #pragma unroll
            for (int k = 0; k < K; ++k) acc = fmaf(wk[k], r[j + k], acc);
            if (ADD) acc += bf2f(sa[e * RS]);
            const bool gv = (unsigned)(l0 + e) < 4096u;
            so[e * RS] = gv ? f2bf(acc) : (u16)0;
        }
    }
}

// ---------------- LayerNorm over channels, in place --------------------------
template<int C>
DEVI void ln_ph(u16* sh, SL s, const float* W, const float* B,
                int elo, int ehi, int l0, float* scr, float* mean, float* rstd) {
    constexpr int P = C / 64;
    const int tid = threadIdx.x;
    const int nP = ehi - elo;
    if (tid < nP * P) {
        const int e = elo + tid / P;
        const int part = tid - (tid / P) * P;
        const u16* row = sh + slotOf(s, part * 64) * SLOT + e * RS;
        float sm = 0.f, sq = 0.f;
        #pragma unroll
        for (int j = 0; j < 8; ++j) {
            shrt8 v = *(const shrt8*)(row + j * 8);
            #pragma unroll
            for (int i = 0; i < 8; ++i) { float f = bf2f((u16)v[i]); sm += f; sq += f * f; }
        }
        scr[tid * 2] = sm; scr[tid * 2 + 1] = sq;
    }
    __syncthreads();
    if (tid < nP) {
        float sm = 0.f, sq = 0.f;
        for (int p = 0; p < P; ++p) { sm += scr[(tid * P + p) * 2]; sq += scr[(tid * P + p) * 2 + 1]; }
        const float mu = sm * (1.0f / C);
        const float va = sq * (1.0f / C) - mu * mu;
        mean[elo + tid] = mu; rstd[elo + tid] = rsqrtf(va + 1e-6f);
    }
    __syncthreads();
    const int nC8 = C / 8, total = nP * nC8;
    for (int t = tid; t < total; t += 512) {
        const int e  = elo + t / nC8;
        const int c0 = (t - (t / nC8) * nC8) * 8;
        const float mu = mean[e], rs = rstd[e];
        const bool gv = (unsigned)(l0 + e) < 4096u;
        u16* p = sh + slotOf(s, c0) * SLOT + e * RS + (c0 & 63);
        shrt8 v = *(const shrt8*)p, o;
        const f32x4 w0 = *(const f32x4*)(W + c0), w1 = *(const f32x4*)(W + c0 + 4);
        const f32x4 b0 = *(const f32x4*)(B + c0), b1 = *(const f32x4*)(B + c0 + 4);
        #pragma unroll
        for (int i = 0; i < 4; ++i) {
            float f = (bf2f((u16)v[i]) - mu) * rs * w0[i] + b0[i];
            o[i] = gv ? (short)f2bf(f) : (short)0;
        }
        #pragma unroll
        for (int i = 0; i < 4; ++i) {
            float f = (bf2f((u16)v[4 + i]) - mu) * rs * w1[i] + b1[i];
            o[4 + i] = gv ? (short)f2bf(f) : (short)0;
        }
        *(shrt8*)p = o;
    }
}

// ---------------- load 64-chan chunk of x, apply LN1, store bf16 -------------
DEVI void norm_load(u16* sh, int slot, const float* xg, int b, int cbase,
                    const float* lnw, const float* lnb,
                    const float* mean, const float* rstd,
                    int elo, int ehi, int l0) {
    const int lane = threadIdx.x & 63;
    const int wv   = threadIdx.x >> 6;
    for (int j = 0; j < 8; ++j) {
        const int o = wv + NW * j;
        const float* p = xg + ((size_t)b * 256 + cbase + o) * 4096;
        const float wo = lnw[cbase + o], bo = lnb[cbase + o];
        u16* r = sh + slot * SLOT + o;
        const int e = elo + lane;
        if (e < ehi) {
            const int l = l0 + e;
            const bool gv = (unsigned)l < 4096u;
            float v = gv ? p[l] : 0.f;
            v = (v - mean[e]) * rstd[e] * wo + bo;
            r[e * RS] = gv ? f2bf(v) : (u16)0;
        }
    }
}

// ---------------- final dw3 + add -> global (coalesced along l) --------------
DEVI void dw3_glob(u16* sh, int inSlot, int addSlot, const float* W, const float* B,
                   float* outg, int b, int l0) {
    const int tid = threadIdx.x;
    #pragma unroll
    for (int k = 0; k < 4; ++k) {
        const int idx = tid + k * 512;          // 2048 = 64 chans x 32 pos
        const int c   = idx >> 5;
        const int e   = 12 + (idx & 31);
        const u16* si = sh + inSlot * SLOT + c;
        float acc = B[c];
        acc = fmaf(W[c * 3 + 0], bf2f(si[(e - 1) * RS]), acc);
        acc = fmaf(W[c * 3 + 1], bf2f(si[e * RS]), acc);
        acc = fmaf(W[c * 3 + 2], bf2f(si[(e + 1) * RS]), acc);
        acc += bf2f(sh[addSlot * SLOT + e * RS + c]);
        outg[((size_t)b * 256 + c) * 4096 + (l0 + e)] = acc;
    }
}

// ============================================================================

enum {
    I_X = 0, I_LN1W, I_LN1B, I_A1PW, I_A1PB, I_A1DW, I_A1DB, I_V1W, I_V1B,
    I_V11W, I_V11B, I_V12W, I_V12B, I_C31W, I_C31B,
    I_LN2W, I_LN2B, I_A2PW, I_A2PB, I_A2DW, I_A2DB, I_V2W, I_V2B,
    I_V21W, I_V21B, I_V22W, I_V22B, I_P2W, I_P2B, I_C32W, I_C32B,
    I_LN3W, I_LN3B, I_A3PW, I_A3PB, I_A3DW, I_A3DB, I_V3W, I_V3B,
    I_V31W, I_V31B, I_V32W, I_V32B, I_P3W, I_P3B, I_C33W, I_C33B
};
enum { W_A1P = 0, W_V1, W_V11, W_V12, W_A2P, W_V2, W_V21, W_V22, W_P2,
       W_A3P, W_V3, W_V31, W_V32, W_P3, W_N };

struct KArgs { const float* p[47]; const u16* w[W_N]; const float* stats; float* out; };
struct CvtArgs { const float* src[W_N]; u16* dst; int off[W_N + 1]; };

__global__ __launch_bounds__(256) void cvt_kernel(CvtArgs a) {
    const int i = blockIdx.x * 256 + threadIdx.x;
    if (i >= a.off[W_N]) return;
    int s = 0;
    while (i >= a.off[s + 1]) ++s;
    a.dst[i] = f2bf(a.src[s][i - a.off[s]]);
}

// LN1 statistics for all (b,l): coalesced along l (lanes = consecutive l).
__global__ __launch_bounds__(256) void ln1pre_kernel(const float* x, float* stats) {
    const int b = blockIdx.x >> 4;                     // 16 blocks of 256 l per batch
    const int l = ((blockIdx.x & 15) << 8) + threadIdx.x;
    const float* p = x + (size_t)b * 256 * 4096 + l;
    float sm = 0.f, sq = 0.f;
    #pragma unroll 4
    for (int c = 0; c < 256; ++c) {
        const float v = p[(size_t)c * 4096];
        sm += v; sq += v * v;
    }
    const float mu = sm * (1.0f / 256.0f);
    const float va = sq * (1.0f / 256.0f) - mu * mu;
    float2 o; o.x = mu; o.y = rsqrtf(va + 1e-6f);
    *(float2*)(stats + 2 * ((size_t)b * 4096 + l)) = o;
}

__global__ __launch_bounds__(512, 6) void convmod_kernel(KArgs a) {
    __shared__ u16 pool[6 * SLOT];                       // 48384 B
    __shared__ float meanA[EXT], rstdA[EXT], meanB[EXT], rstdB[EXT];
    __shared__ float scr[256];

    const int b    = blockIdx.x >> 7;
    const int tile = blockIdx.x & 127;
    const int l0   = tile * 32 - 12;
    const float* xg = a.p[I_X];
    u16* sh = pool;

    // pre: LN1 stats from workspace
    if (threadIdx.x < EXT) {
        const int l = l0 + (int)threadIdx.x;
        float mu = 0.f, rs = 1.f;
        if ((unsigned)l < 4096u) {
            const float2 st = *(const float2*)(a.stats + 2 * ((size_t)b * 4096 + l));
            mu = st.x; rs = st.y;
        }
        meanA[threadIdx.x] = mu; rstdA[threadIdx.x] = rs;
    }
    __syncthreads();
    // P0
    norm_load(sh, 0, xg, b,  0, a.p[I_LN1W], a.p[I_LN1B], meanA, rstdA, 0, EXT, l0);
    norm_load(sh, 1, xg, b, 64, a.p[I_LN1W], a.p[I_LN1B], meanA, rstdA, 0, EXT, l0);
    __syncthreads();
    // P1: g1, pv1, pwv12
    pw_mfma<64, 64, true,  false, false>(sh, SL{0,-1,-1}, SL{2,-1,-1}, a.w[W_A1P], a.p[I_A1PB], 0, 56, l0);
    pw_mfma<64, 64, false, false, false>(sh, SL{0,-1,-1}, SL{3,-1,-1}, a.w[W_V1],  a.p[I_V1B],  3, 53, l0);
    pw_mfma<64, 64, false, false, false>(sh, SL{1,-1,-1}, SL{4,-1,-1}, a.w[W_V12], a.p[I_V12B], 2, 54, l0);
    __syncthreads();
    // P2: a1 -> S5, t1 = a1*pv1 in-place S3
    dw_mul<64, 7, 3, 8, false>(sh, SL{2,-1,-1}, SL{5,-1,-1}, SL{3,-1,-1}, a.p[I_A1DW], a.p[I_A1DB], 3, 53);
    __syncthreads();
    // P3: mul1 -> S2, x1low = dw3(S4)+S5 -> S1
    pw_mfma<64, 64, false, false, false>(sh, SL{3,-1,-1}, SL{2,-1,-1}, a.w[W_V11], a.p[I_V11B], 3, 53, l0);
    dw_ph<64, 3, 1, true>(sh, SL{4,-1,-1}, SL{5,-1,-1}, SL{1,-1,-1}, a.p[I_C31W], a.p[I_C31B], 3, 53, l0);
    __syncthreads();
    // P4: ln2 over {S1,S2}
    ln_ph<128>(sh, SL{1,2,-1}, a.p[I_LN2W], a.p[I_LN2B], 3, 53, l0, scr, meanB, rstdB);
    __syncthreads();
    // P5: xs2n -> S0, g2 -> {S3,S4}, pv2 INPL {S1,S2}
    norm_load(sh, 0, xg, b, 128, a.p[I_LN1W], a.p[I_LN1B], meanA, rstdA, 6, 50, l0);
    pw_mfma<128, 128, true,  false, false>(sh, SL{1,2,-1}, SL{3,4,-1}, a.w[W_A2P], a.p[I_A2PB], 3, 53, l0);
    pw_mfma<128, 128, false, false, true >(sh, SL{1,2,-1}, SL{1,2,-1}, a.w[W_V2],  a.p[I_V2B],  7, 49, l0);
    __syncthreads();
    // P6: pwv22 S0 -> S5, a2 = dw9 INPL {S3,S4} + t2 in-place {S1,S2}
    pw_mfma<64, 64, false, false, false>(sh, SL{0,-1,-1}, SL{5,-1,-1}, a.w[W_V22], a.p[I_V22B], 6, 50, l0);
    dw_mul<128, 9, 4, 16, true>(sh, SL{3,4,-1}, SL{3,4,-1}, SL{1,2,-1}, a.p[I_A2DW], a.p[I_A2DB], 7, 49);
    __syncthreads();
    // P7: p2a {S3,S4} -> S0, mul2 INPL {S1,S2}
    pw_mfma<64, 128, false, false, false>(sh, SL{3,4,-1}, SL{0,-1,-1}, a.w[W_P2], a.p[I_P2B], 7, 49, l0);
    pw_mfma<128, 128, false, false, true >(sh, SL{1,2,-1}, SL{1,2,-1}, a.w[W_V21], a.p[I_V21B], 7, 49, l0);
    __syncthreads();
    // P8: x2low = dw3(S5)+S0 -> S3
    dw_ph<64, 3, 1, true>(sh, SL{5,-1,-1}, SL{0,-1,-1}, SL{3,-1,-1}, a.p[I_C32W], a.p[I_C32B], 7, 49, l0);
    __syncthreads();
    // P9: ln3 over {S3,S1,S2}
    ln_ph<192>(sh, SL{3,1,2}, a.p[I_LN3W], a.p[I_LN3B], 7, 49, l0, scr, meanB, rstdB);
    __syncthreads();
    // P10: g3 -> {S4,S5,S0}, pv3 INPL {S3,S1,S2}
    pw_mfma<192, 192, true,  false, false>(sh, SL{3,1,2}, SL{4,5,0}, a.w[W_A3P], a.p[I_A3PB], 7, 49, l0);
    pw_mfma<192, 192, false, false, true >(sh, SL{3,1,2}, SL{3,1,2}, a.w[W_V3],  a.p[I_V3B],  12, 44, l0);
    __syncthreads();
    // P11: a3 = dw11 INPL {S4,S5,S0} + t3 in-place {S3,S1,S2}
    dw_mul<192, 11, 5, 16, true>(sh, SL{4,5,0}, SL{4,5,0}, SL{3,1,2}, a.p[I_A3DW], a.p[I_A3DB], 12, 44);
    __syncthreads();
    // P12: mul3 -> out[64:256], p3a INPL {S4,S5,S0} -> S4, xs3n -> S5
    pw_mfma<192, 192, false, true,  false>(sh, SL{3,1,2}, SL{-1,-1,-1}, a.w[W_V31], a.p[I_V31B], 12, 44, l0, a.out, b, 64);
    pw_mfma<64, 192, false, false, true >(sh, SL{4,5,0}, SL{4,-1,-1}, a.w[W_P3],  a.p[I_P3B],  12, 44, l0);
    norm_load(sh, 5, xg, b, 192, a.p[I_LN1W], a.p[I_LN1B], meanA, rstdA, 11, 45, l0);
    __syncthreads();
    // P13: pwv32 S5 -> S0
    pw_mfma<64, 64, false, false, false>(sh, SL{5,-1,-1}, SL{0,-1,-1}, a.w[W_V32], a.p[I_V32B], 11, 45, l0);
    __syncthreads();
    // P14: x3 = dw3(S0)+S4 -> out[0:64]
    dw3_glob(sh, 0, 4, a.p[I_C33W], a.p[I_C33B], a.out, b, l0);
}

extern "C" void kernel_launch(void* const* d_in, const int* in_sizes, int n_in,
                              void* d_out, int out_size, void* d_ws, size_t ws_size,
                              hipStream_t stream) {
    (void)in_sizes; (void)n_in; (void)out_size; (void)ws_size;
    static const int widx[W_N] = { I_A1PW, I_V1W, I_V11W, I_V12W, I_A2PW, I_V2W,
                                   I_V21W, I_V22W, I_P2W, I_A3PW, I_V3W, I_V31W,
                                   I_V32W, I_P3W };
    static const int wsz[W_N]  = { 4096, 4096, 4096, 4096, 16384, 16384, 16384,
                                   4096, 8192, 36864, 36864, 36864, 4096, 12288 };
    CvtArgs ca; KArgs ka;
    int off = 0;
    for (int i = 0; i < W_N; ++i) {
        ca.src[i] = (const float*)d_in[widx[i]];
        ca.off[i] = off;
        off += wsz[i];
    }
    ca.off[W_N] = off;                       // 204800 elems = 409600 B in d_ws
    ca.dst = (u16*)d_ws;
    for (int i = 0; i < 47; ++i) ka.p[i] = (const float*)d_in[i];
    for (int i = 0; i < W_N; ++i) ka.w[i] = (const u16*)d_ws + ca.off[i];
    // LN1 stats region: after weights, 8-B aligned; 32*4096*2 f32 = 1 MiB.
    const size_t stats_off = ((size_t)off * sizeof(u16) + 255) & ~(size_t)255;
    float* stats = (float*)((char*)d_ws + stats_off);
    ka.stats = stats;
    ka.out = (float*)d_out;

    cvt_kernel<<<dim3((off + 255) / 256), dim3(256), 0, stream>>>(ca);
    ln1pre_kernel<<<dim3(32 * 16), dim3(256), 0, stream>>>((const float*)d_in[I_X], stats);
    convmod_kernel<<<dim3(32 * 128), dim3(512), 0, stream>>>(ka);
}

// Round 2
// 691.768 us; speedup vs baseline: 1.2386x; 1.1947x over previous
//
#include <hip/hip_runtime.h>
#include <cmath>

// ============================================================================
// ConvMod1D fused kernel — round 4: TL=64 tiles (halo amortization).
// TL=64 positions/block (halo 12 each side -> EXT=88). Halo overhead drops
// 1.75x -> 1.375x: −21% of ALL per-position work (MFMA+VALU), and blocks
// halve (2048) -> half the barrier crossings per useful output.
// 6 LDS slots of [pos][chan] bf16, RS=72 u16 -> 76.0 KB LDS => 2 blocks/CU.
// pw_mfma: 6 n-tiles of 16 (96 >= 88), wave grid 4M x 2N, NT=3/wave.
// dw_mul windows widened so in-place staging keeps <=1 task/wave:
//   a1 WIN=16 (6 tasks), a2 WIN=19 (8 tasks), a3 WIN=32 (6 tasks, r[42]).
//
// Slot schedule (S0..S5, liveness checked; stale data only ever feeds
// masked MFMA columns / is finite bf16). Ranges for TL=64:
//  pre: meanA/rstdA <- stats | P0 xs0n->S0, xs1n->S1 [0,88)
//  P1 g1->S2 [0,88), pv1->S3 [3,85), pwv12->S4 [2,86)
//  P2 a1=dw7(S2)->S5 + t1=a1*pv1 in-place S3   [3,85)
//  P3 mul1=pw(S3)->S2, x1low=dw3(S4)+S5->S1    [3,85)
//  P4 ln2 over {S1,S2} [3,85)
//  P5 xs2n->S0 [6,82), g2->{S3,S4} [3,85), pv2 INPL {S1,S2} [7,81)
//  P6 pwv22: S0->S5 [6,82), a2=dw9 INPL {S3,S4} + t2 in-place {S1,S2} [7,81)
//  P7 p2a: {S3,S4}->S0 [7,81), mul2 INPL {S1,S2} [7,81)
//  P8 x2low=dw3(S5)+S0->S3 [7,81)
//  P9 ln3 over {S3,S1,S2} [7,81)
//  P10 g3->{S4,S5,S0} [7,81), pv3 INPL {S3,S1,S2} [12,76)
//  P11 a3=dw11 INPL {S4,S5,S0} + t3 in-place {S3,S1,S2} [12,76)
//  P12 mul3: pw(t3)->OUT[64:256], p3a INPL {S4,S5,S0}->S4, xs3n->S5 [11,77)
//  P13 pwv32: S5->S0 [11,77)
//  P14 x3=dw3(S0)+S4->OUT[0:64] [12,76)
// ============================================================================

using u16 = unsigned short;
typedef short shrt8 __attribute__((ext_vector_type(8)));
typedef short shrt4 __attribute__((ext_vector_type(4)));
typedef float f32x4 __attribute__((ext_vector_type(4)));

#define DEVI __device__ __forceinline__

static constexpr int TL   = 64;          // useful positions per block
static constexpr int EXT  = 88;          // 64 useful + 2*12 halo
static constexpr int RS   = 72;          // row stride in u16 (64 + 8 pad)
static constexpr int SLOT = EXT * RS;    // 6336 u16 = 12672 B
static constexpr int NW   = 8;

DEVI u16 f2bf(float f) {                 // RNE fp32 -> bf16
    unsigned u = __float_as_uint(f);
    u += 0x7FFFu + ((u >> 16) & 1u);
    return (u16)(u >> 16);
}
DEVI float bf2f(u16 h) { return __uint_as_float(((unsigned)h) << 16); }

// exact-GELU via Abramowitz-Stegun 7.1.26 erf (|err| <= 1.5e-7, branch-free)
DEVI float gelu_f(float x) {
    const float y  = x * 0.70710678118654752f;
    const float ay = fabsf(y);
    const float t  = __builtin_amdgcn_rcpf(fmaf(0.3275911f, ay, 1.0f));
    float p = 1.061405429f;
    p = fmaf(p, t, -1.453152027f);
    p = fmaf(p, t,  1.421413741f);
    p = fmaf(p, t, -0.284496736f);
    p = fmaf(p, t,  0.254829592f);
    float er = 1.0f - p * t * __expf(-ay * ay);
    er = copysignf(er, y);
    return 0.5f * x * (1.0f + er);
}

struct SL { int a, b, c; };
DEVI int slotOf(SL s, int ch) { return ch < 64 ? s.a : (ch < 128 ? s.b : s.c); }

// ---------------- pointwise conv via MFMA ------------------------------------
// 6 n-tiles of 16 positions (96 cols covering EXT=88, tail masked by clamp).
// INPL: out slots alias in slots -> barrier between k-loop (reads) and store.
template<int O, int C, bool GELU, bool TOG, bool INPL>
DEVI void pw_mfma(u16* sh, SL in, SL out, const u16* Wb, const float* bias,
                  int elo, int ehi, int l0,
                  float* outg = nullptr, int bidx = 0, int ochan = 0) {
    constexpr int MR = O / 64;           // m-tiles per wave (4 m-splits)
    constexpr int KT = C / 32;
    constexpr int NT = 3;                // n-tiles per wave (2 n-splits)
    const int lane = threadIdx.x & 63;
    const int wv   = threadIdx.x >> 6;
    const int mw = wv >> 1, nw = wv & 1;
    const int col  = lane & 15;
    const int quad = lane >> 4;
    const int mrow = mw * (MR * 16) + col;
    const int kq   = quad * 8;
    const int crow = mw * (MR * 16) + quad * 4;

    f32x4 acc[MR][NT];
    #pragma unroll
    for (int mi = 0; mi < MR; ++mi) {
        const f32x4 bv = *(const f32x4*)(bias + crow + mi * 16);
        #pragma unroll
        for (int ni = 0; ni < NT; ++ni) acc[mi][ni] = bv;
    }
    bool act[NT]; int bpos[NT];
    #pragma unroll
    for (int ni = 0; ni < NT; ++ni) {
        const int nt = nw * NT + ni;
        act[ni] = (nt * 16 < ehi) && (nt * 16 + 16 > elo);
        int p = nt * 16 + col; if (p > EXT - 1) p = EXT - 1;  // masked cols only
        bpos[ni] = p;
    }
    #pragma unroll
    for (int kt = 0; kt < KT; ++kt) {
        shrt8 af[MR];
        #pragma unroll
        for (int mi = 0; mi < MR; ++mi)
            af[mi] = *(const shrt8*)(Wb + (size_t)(mrow + mi * 16) * C + kt * 32 + kq);
        const int k0 = kt * 32;
        const u16* bs = sh + slotOf(in, k0) * SLOT + ((k0 & 63) + kq);
        #pragma unroll
        for (int ni = 0; ni < NT; ++ni) {
            if (!act[ni]) continue;
            const shrt8 bf = *(const shrt8*)(bs + bpos[ni] * RS);
            #pragma unroll
            for (int mi = 0; mi < MR; ++mi)
                acc[mi][ni] = __builtin_amdgcn_mfma_f32_16x16x32_bf16(af[mi], bf, acc[mi][ni], 0, 0, 0);
        }
    }
    if (INPL) __syncthreads();           // all reads done before any store
    #pragma unroll
    for (int ni = 0; ni < NT; ++ni) {
        if (!act[ni]) continue;
        const int e = (nw * NT + ni) * 16 + col;
        if (e < elo || e >= ehi) continue;
        const int l = l0 + e;
        #pragma unroll
        for (int mi = 0; mi < MR; ++mi) {
            f32x4 v = acc[mi][ni];
            if (GELU) { v[0]=gelu_f(v[0]); v[1]=gelu_f(v[1]); v[2]=gelu_f(v[2]); v[3]=gelu_f(v[3]); }
            const int ch = crow + mi * 16;
            if (TOG) {
                float* og = outg + ((size_t)bidx * 256 + ochan + ch) * 4096 + l;
                og[0] = v[0]; og[4096] = v[1]; og[2*4096] = v[2]; og[3*4096] = v[3];
            } else {
                const bool gv = (unsigned)l < 4096u;
                shrt4 pk;
                pk[0] = gv ? (short)f2bf(v[0]) : (short)0;
                pk[1] = gv ? (short)f2bf(v[1]) : (short)0;
                pk[2] = gv ? (short)f2bf(v[2]) : (short)0;
                pk[3] = gv ? (short)f2bf(v[3]) : (short)0;
                *(shrt4*)(sh + slotOf(out, ch) * SLOT + e * RS + (ch & 63)) = pk;
            }
        }
    }
}

// ---------------- depthwise conv fused with t = a*v, optional in-place -------
// One window of WIN positions per wave (tasks = (C/64)*nwin must be <= NW).
// INPL: a-output aliases the input slots -> read window into regs, barrier,
// then write. The v-multiply is element-wise in-place (thread-private RMW).
template<int C, int K, int PAD, int WIN, bool INPL>
DEVI void dw_mul(u16* sh, SL g, SL ao, SL v, const float* W, const float* bias,
                 int elo, int ehi) {
    const int lane = threadIdx.x & 63;
    const int wv   = threadIdx.x >> 6;
    const int nwin  = (ehi - elo + WIN - 1) / WIN;
    const int tasks = (C / 64) * nwin;       // <= NW by construction
    const bool have = wv < tasks;
    float r[K + WIN - 1];
    float wk[K];
    float bo = 0.f;
    int c = 0, e0 = 0;
    if (have) {
        const int cb = wv / nwin, wi = wv - cb * nwin;
        c = cb * 64 + lane;
        #pragma unroll
        for (int k = 0; k < K; ++k) wk[k] = W[c * K + k];
        bo = bias[c];
        e0 = elo + wi * WIN;
        const u16* si = sh + slotOf(g, c) * SLOT + lane;
        #pragma unroll
        for (int m = 0; m < K + WIN - 1; ++m) {
            int e = e0 - PAD + m; if (e > EXT - 1) e = EXT - 1;  // feeds masked outputs only
            r[m] = bf2f(si[e * RS]);
        }
    }
    if (INPL) __syncthreads();               // all reads done before any write
    if (have) {
        u16* sa = sh + slotOf(ao, c) * SLOT + lane;
        u16* sv = sh + slotOf(v, c) * SLOT + lane;
        #pragma unroll
        for (int j = 0; j < WIN; ++j) {
            const int e = e0 + j;
            if (e >= ehi) break;
            float acc = bo;
            #pragma unroll
            for (int k = 0; k < K; ++k) acc = fmaf(wk[k], r[j + k], acc);
            sa[e * RS] = f2bf(acc);                               // a
            sv[e * RS] = f2bf(acc * bf2f(sv[e * RS]));            // t = a*v (v masked 0 OOB)
        }
    }
}

// ---------------- depthwise conv (VALU), chan-per-lane, 8-pos windows --------
template<int C, int K, int PAD, bool ADD>
DEVI void dw_ph(u16* sh, SL in, SL add, SL out, const float* W, const float* bias,
                int elo, int ehi, int l0) {
    const int lane = threadIdx.x & 63;
    const int wv   = threadIdx.x >> 6;
    const int nwin = (ehi - elo + 7) >> 3;
    const int tasks = (C / 64) * nwin;
    for (int t = wv; t < tasks; t += NW) {
        const int cb = t / nwin, wi = t - cb * nwin;
        const int c = cb * 64 + lane;
        float wk[K];
        #pragma unroll
        for (int k = 0; k < K; ++k) wk[k] = W[c * K + k];
        const float bo = bias[c];
        const int e0 = elo + wi * 8;
        const u16* si = sh + slotOf(in, c) * SLOT + lane;
        const u16* sa = ADD ? (sh + slotOf(add, c) * SLOT + lane) : nullptr;
        u16* so = sh + slotOf(out, c) * SLOT + lane;
        float r[K + 7];
        #pragma unroll
        for (int m = 0; m < K + 7; ++m) {
            int e = e0 - PAD + m; if (e > EXT - 1) e = EXT - 1;  // feeds masked outputs only
            r[m] = bf2f(si[e * RS]);
        }
        #pragma unroll
        for (int j = 0; j < 8; ++j) {
            const int e = e0 + j;
            if (e >= ehi) break;
            float acc = bo;
            #pragma unroll
            for (int k = 0; k < K; ++k) acc = fmaf(wk[k], r[j + k], acc);
            if (ADD) acc += bf2f(sa[e * RS]);
            const bool gv = (unsigned)(l0 + e) < 4096u;
            so[e * RS] = gv ? f2bf(acc) : (u16)0;
        }
    }
}

// ---------------- LayerNorm over channels, in place --------------------------
template<int C>
DEVI void ln_ph(u16* sh, SL s, const float* W, const float* B,
                int elo, int ehi, int l0, float* scr, float* mean, float* rstd) {
    constexpr int P = C / 64;
    const int tid = threadIdx.x;
    const int nP = ehi - elo;
    if (tid < nP * P) {
        const int e = elo + tid / P;
        const int part = tid - (tid / P) * P;
        const u16* row = sh + slotOf(s, part * 64) * SLOT + e * RS;
        float sm = 0.f, sq = 0.f;
        #pragma unroll
        for (int j = 0; j < 8; ++j) {
            shrt8 v = *(const shrt8*)(row + j * 8);
            #pragma unroll
            for (int i = 0; i < 8; ++i) { float f = bf2f((u16)v[i]); sm += f; sq += f * f; }
        }
        scr[tid * 2] = sm; scr[tid * 2 + 1] = sq;
    }
    __syncthreads();
    if (tid < nP) {
        float sm = 0.f, sq = 0.f;
        for (int p = 0; p < P; ++p) { sm += scr[(tid * P + p) * 2]; sq += scr[(tid * P + p) * 2 + 1]; }
        const float mu = sm * (1.0f / C);
        const float va = sq * (1.0f / C) - mu * mu;
        mean[elo + tid] = mu; rstd[elo + tid] = rsqrtf(va + 1e-6f);
    }
    __syncthreads();
    const int nC8 = C / 8, total = nP * nC8;
    for (int t = tid; t < total; t += 512) {
        const int e  = elo + t / nC8;
        const int c0 = (t - (t / nC8) * nC8) * 8;
        const float mu = mean[e], rs = rstd[e];
        const bool gv = (unsigned)(l0 + e) < 4096u;
        u16* p = sh + slotOf(s, c0) * SLOT + e * RS + (c0 & 63);
        shrt8 v = *(const shrt8*)p, o;
        const f32x4 w0 = *(const f32x4*)(W + c0), w1 = *(const f32x4*)(W + c0 + 4);
        const f32x4 b0 = *(const f32x4*)(B + c0), b1 = *(const f32x4*)(B + c0 + 4);
        #pragma unroll
        for (int i = 0; i < 4; ++i) {
            float f = (bf2f((u16)v[i]) - mu) * rs * w0[i] + b0[i];
            o[i] = gv ? (short)f2bf(f) : (short)0;
        }
        #pragma unroll
        for (int i = 0; i < 4; ++i) {
            float f = (bf2f((u16)v[4 + i]) - mu) * rs * w1[i] + b1[i];
            o[4 + i] = gv ? (short)f2bf(f) : (short)0;
        }
        *(shrt8*)p = o;
    }
}

// ---------------- load 64-chan chunk of x, apply LN1, store bf16 -------------
DEVI void norm_load(u16* sh, int slot, const float* xg, int b, int cbase,
                    const float* lnw, const float* lnb,
                    const float* mean, const float* rstd,
                    int elo, int ehi, int l0) {
    const int lane = threadIdx.x & 63;
    const int wv   = threadIdx.x >> 6;
    #pragma unroll
    for (int j = 0; j < 8; ++j) {
        const int o = wv + NW * j;
        const float* p = xg + ((size_t)b * 256 + cbase + o) * 4096;
        const float wo = lnw[cbase + o], bo = lnb[cbase + o];
        u16* r = sh + slot * SLOT + o;
        #pragma unroll
        for (int part = 0; part < 2; ++part) {
            const int e = elo + lane + part * 64;
            if (e < ehi) {
                const int l = l0 + e;
                const bool gv = (unsigned)l < 4096u;
                float v = gv ? p[l] : 0.f;
                v = (v - mean[e]) * rstd[e] * wo + bo;
                r[e * RS] = gv ? f2bf(v) : (u16)0;
            }
        }
    }
}

// ---------------- final dw3 + add -> global (coalesced along l) --------------
DEVI void dw3_glob(u16* sh, int inSlot, int addSlot, const float* W, const float* B,
                   float* outg, int b, int l0) {
    const int tid = threadIdx.x;
    #pragma unroll
    for (int k = 0; k < 8; ++k) {
        const int idx = tid + k * 512;          // 4096 = 64 chans x 64 pos
        const int c   = idx >> 6;
        const int e   = 12 + (idx & 63);
        const u16* si = sh + inSlot * SLOT + c;
        float acc = B[c];
        acc = fmaf(W[c * 3 + 0], bf2f(si[(e - 1) * RS]), acc);
        acc = fmaf(W[c * 3 + 1], bf2f(si[e * RS]), acc);
        acc = fmaf(W[c * 3 + 2], bf2f(si[(e + 1) * RS]), acc);
        acc += bf2f(sh[addSlot * SLOT + e * RS + c]);
        outg[((size_t)b * 256 + c) * 4096 + (l0 + e)] = acc;
    }
}

// ============================================================================

enum {
    I_X = 0, I_LN1W, I_LN1B, I_A1PW, I_A1PB, I_A1DW, I_A1DB, I_V1W, I_V1B,
    I_V11W, I_V11B, I_V12W, I_V12B, I_C31W, I_C31B,
    I_LN2W, I_LN2B, I_A2PW, I_A2PB, I_A2DW, I_A2DB, I_V2W, I_V2B,
    I_V21W, I_V21B, I_V22W, I_V22B, I_P2W, I_P2B, I_C32W, I_C32B,
    I_LN3W, I_LN3B, I_A3PW, I_A3PB, I_A3DW, I_A3DB, I_V3W, I_V3B,
    I_V31W, I_V31B, I_V32W, I_V32B, I_P3W, I_P3B, I_C33W, I_C33B
};
enum { W_A1P = 0, W_V1, W_V11, W_V12, W_A2P, W_V2, W_V21, W_V22, W_P2,
       W_A3P, W_V3, W_V31, W_V32, W_P3, W_N };

struct KArgs { const float* p[47]; const u16* w[W_N]; const float* stats; float* out; };
struct CvtArgs { const float* src[W_N]; u16* dst; int off[W_N + 1]; };

__global__ __launch_bounds__(256) void cvt_kernel(CvtArgs a) {
    const int i = blockIdx.x * 256 + threadIdx.x;
    if (i >= a.off[W_N]) return;
    int s = 0;
    while (i >= a.off[s + 1]) ++s;
    a.dst[i] = f2bf(a.src[s][i - a.off[s]]);
}

// LN1 statistics for all (b,l): coalesced along l (lanes = consecutive l).
__global__ __launch_bounds__(256) void ln1pre_kernel(const float* x, float* stats) {
    const int b = blockIdx.x >> 4;                     // 16 blocks of 256 l per batch
    const int l = ((blockIdx.x & 15) << 8) + threadIdx.x;
    const float* p = x + (size_t)b * 256 * 4096 + l;
    float sm = 0.f, sq = 0.f;
    #pragma unroll 4
    for (int c = 0; c < 256; ++c) {
        const float v = p[(size_t)c * 4096];
        sm += v; sq += v * v;
    }
    const float mu = sm * (1.0f / 256.0f);
    const float va = sq * (1.0f / 256.0f) - mu * mu;
    float2 o; o.x = mu; o.y = rsqrtf(va + 1e-6f);
    *(float2*)(stats + 2 * ((size_t)b * 4096 + l)) = o;
}

__global__ __launch_bounds__(512, 4) void convmod_kernel(KArgs a) {
    __shared__ u16 pool[6 * SLOT];                       // 76032 B
    __shared__ float meanA[EXT], rstdA[EXT], meanB[EXT], rstdB[EXT];
    __shared__ float scr[448];

    const int b    = blockIdx.x >> 6;
    const int tile = blockIdx.x & 63;
    const int l0   = tile * TL - 12;
    const float* xg = a.p[I_X];
    u16* sh = pool;

    // pre: LN1 stats from workspace
    if (threadIdx.x < EXT) {
        const int l = l0 + (int)threadIdx.x;
        float mu = 0.f, rs = 1.f;
        if ((unsigned)l < 4096u) {
            const float2 st = *(const float2*)(a.stats + 2 * ((size_t)b * 4096 + l));
            mu = st.x; rs = st.y;
        }
        meanA[threadIdx.x] = mu; rstdA[threadIdx.x] = rs;
    }
    __syncthreads();
    // P0
    norm_load(sh, 0, xg, b,  0, a.p[I_LN1W], a.p[I_LN1B], meanA, rstdA, 0, EXT, l0);
    norm_load(sh, 1, xg, b, 64, a.p[I_LN1W], a.p[I_LN1B], meanA, rstdA, 0, EXT, l0);
    __syncthreads();
    // P1: g1, pv1, pwv12
    pw_mfma<64, 64, true,  false, false>(sh, SL{0,-1,-1}, SL{2,-1,-1}, a.w[W_A1P], a.p[I_A1PB], 0, 88, l0);
    pw_mfma<64, 64, false, false, false>(sh, SL{0,-1,-1}, SL{3,-1,-1}, a.w[W_V1],  a.p[I_V1B],  3, 85, l0);
    pw_mfma<64, 64, false, false, false>(sh, SL{1,-1,-1}, SL{4,-1,-1}, a.w[W_V12], a.p[I_V12B], 2, 86, l0);
    __syncthreads();
    // P2: a1 -> S5, t1 = a1*pv1 in-place S3
    dw_mul<64, 7, 3, 16, false>(sh, SL{2,-1,-1}, SL{5,-1,-1}, SL{3,-1,-1}, a.p[I_A1DW], a.p[I_A1DB], 3, 85);
    __syncthreads();
    // P3: mul1 -> S2, x1low = dw3(S4)+S5 -> S1
    pw_mfma<64, 64, false, false, false>(sh, SL{3,-1,-1}, SL{2,-1,-1}, a.w[W_V11], a.p[I_V11B], 3, 85, l0);
    dw_ph<64, 3, 1, true>(sh, SL{4,-1,-1}, SL{5,-1,-1}, SL{1,-1,-1}, a.p[I_C31W], a.p[I_C31B], 3, 85, l0);
    __syncthreads();
    // P4: ln2 over {S1,S2}
    ln_ph<128>(sh, SL{1,2,-1}, a.p[I_LN2W], a.p[I_LN2B], 3, 85, l0, scr, meanB, rstdB);
    __syncthreads();
    // P5: xs2n -> S0, g2 -> {S3,S4}, pv2 INPL {S1,S2}
    norm_load(sh, 0, xg, b, 128, a.p[I_LN1W], a.p[I_LN1B], meanA, rstdA, 6, 82, l0);
    pw_mfma<128, 128, true,  false, false>(sh, SL{1,2,-1}, SL{3,4,-1}, a.w[W_A2P], a.p[I_A2PB], 3, 85, l0);
    pw_mfma<128, 128, false, false, true >(sh, SL{1,2,-1}, SL{1,2,-1}, a.w[W_V2],  a.p[I_V2B],  7, 81, l0);
    __syncthreads();
    // P6: pwv22 S0 -> S5, a2 = dw9 INPL {S3,S4} + t2 in-place {S1,S2}
    pw_mfma<64, 64, false, false, false>(sh, SL{0,-1,-1}, SL{5,-1,-1}, a.w[W_V22], a.p[I_V22B], 6, 82, l0);
    dw_mul<128, 9, 4, 19, true>(sh, SL{3,4,-1}, SL{3,4,-1}, SL{1,2,-1}, a.p[I_A2DW], a.p[I_A2DB], 7, 81);
    __syncthreads();
    // P7: p2a {S3,S4} -> S0, mul2 INPL {S1,S2}
    pw_mfma<64, 128, false, false, false>(sh, SL{3,4,-1}, SL{0,-1,-1}, a.w[W_P2], a.p[I_P2B], 7, 81, l0);
    pw_mfma<128, 128, false, false, true >(sh, SL{1,2,-1}, SL{1,2,-1}, a.w[W_V21], a.p[I_V21B], 7, 81, l0);
    __syncthreads();
    // P8: x2low = dw3(S5)+S0 -> S3
    dw_ph<64, 3, 1, true>(sh, SL{5,-1,-1}, SL{0,-1,-1}, SL{3,-1,-1}, a.p[I_C32W], a.p[I_C32B], 7, 81, l0);
    __syncthreads();
    // P9: ln3 over {S3,S1,S2}
    ln_ph<192>(sh, SL{3,1,2}, a.p[I_LN3W], a.p[I_LN3B], 7, 81, l0, scr, meanB, rstdB);
    __syncthreads();
    // P10: g3 -> {S4,S5,S0}, pv3 INPL {S3,S1,S2}
    pw_mfma<192, 192, true,  false, false>(sh, SL{3,1,2}, SL{4,5,0}, a.w[W_A3P], a.p[I_A3PB], 7, 81, l0);
    pw_mfma<192, 192, false, false, true >(sh, SL{3,1,2}, SL{3,1,2}, a.w[W_V3],  a.p[I_V3B],  12, 76, l0);
    __syncthreads();
    // P11: a3 = dw11 INPL {S4,S5,S0} + t3 in-place {S3,S1,S2}
    dw_mul<192, 11, 5, 32, true>(sh, SL{4,5,0}, SL{4,5,0}, SL{3,1,2}, a.p[I_A3DW], a.p[I_A3DB], 12, 76);
    __syncthreads();
    // P12: mul3 -> out[64:256], p3a INPL {S4,S5,S0} -> S4, xs3n -> S5
    pw_mfma<192, 192, false, true,  false>(sh, SL{3,1,2}, SL{-1,-1,-1}, a.w[W_V31], a.p[I_V31B], 12, 76, l0, a.out, b, 64);
    pw_mfma<64, 192, false, false, true >(sh, SL{4,5,0}, SL{4,-1,-1}, a.w[W_P3],  a.p[I_P3B],  12, 76, l0);
    norm_load(sh, 5, xg, b, 192, a.p[I_LN1W], a.p[I_LN1B], meanA, rstdA, 11, 77, l0);
    __syncthreads();
    // P13: pwv32 S5 -> S0
    pw_mfma<64, 64, false, false, false>(sh, SL{5,-1,-1}, SL{0,-1,-1}, a.w[W_V32], a.p[I_V32B], 11, 77, l0);
    __syncthreads();
    // P14: x3 = dw3(S0)+S4 -> out[0:64]
    dw3_glob(sh, 0, 4, a.p[I_C33W], a.p[I_C33B], a.out, b, l0);
}

extern "C" void kernel_launch(void* const* d_in, const int* in_sizes, int n_in,
                              void* d_out, int out_size, void* d_ws, size_t ws_size,
                              hipStream_t stream) {
    (void)in_sizes; (void)n_in; (void)out_size; (void)ws_size;
    static const int widx[W_N] = { I_A1PW, I_V1W, I_V11W, I_V12W, I_A2PW, I_V2W,
                                   I_V21W, I_V22W, I_P2W, I_A3PW, I_V3W, I_V31W,
                                   I_V32W, I_P3W };
    static const int wsz[W_N]  = { 4096, 4096, 4096, 4096, 16384, 16384, 16384,
                                   4096, 8192, 36864, 36864, 36864, 4096, 12288 };
    CvtArgs ca; KArgs ka;
    int off = 0;
    for (int i = 0; i < W_N; ++i) {
        ca.src[i] = (const float*)d_in[widx[i]];
        ca.off[i] = off;
        off += wsz[i];
    }
    ca.off[W_N] = off;                       // 204800 elems = 409600 B in d_ws
    ca.dst = (u16*)d_ws;
    for (int i = 0; i < 47; ++i) ka.p[i] = (const float*)d_in[i];
    for (int i = 0; i < W_N; ++i) ka.w[i] = (const u16*)d_ws + ca.off[i];
    // LN1 stats region: after weights, 256-B aligned; 32*4096*2 f32 = 1 MiB.
    const size_t stats_off = ((size_t)off * sizeof(u16) + 255) & ~(size_t)255;
    float* stats = (float*)((char*)d_ws + stats_off);
    ka.stats = stats;
    ka.out = (float*)d_out;

    cvt_kernel<<<dim3((off + 255) / 256), dim3(256), 0, stream>>>(ca);
    ln1pre_kernel<<<dim3(32 * 16), dim3(256), 0, stream>>>((const float*)d_in[I_X], stats);
    convmod_kernel<<<dim3(32 * 64), dim3(512), 0, stream>>>(ka);
}